// Round 17
// baseline (74.277 us; speedup 1.0000x reference)
//
#include <hip/hip_runtime.h>

#define LOG2E 1.44269504088896340736f

constexpr int C_ = 64, H_ = 192, W_ = 192;
constexpr int WQ_ = 48, L_ = 2304;          // 48*48 tokens per offset
constexpr int KVB = 64;                      // key tile
constexpr int NMT = L_ / KVB;                // 36 key tiles
constexpr int QROWS = 32;                    // q-rows per block
constexpr int NQT = L_ / QROWS;              // 72
constexpr int NBLK = 32 * NQT;               // 2304 attn blocks
constexpr int NCOL = 18432;                  // x float4-columns: 2*192*48
constexpr int PBLK = (NCOL / 64) * 4;        // proj blocks: 288 col-groups x 4 j

typedef _Float16 half8  __attribute__((ext_vector_type(8)));
typedef short    bf16x8 __attribute__((ext_vector_type(8)));
typedef float    f32x16 __attribute__((ext_vector_type(16)));
typedef uint     u32x2  __attribute__((ext_vector_type(2)));
typedef uint     u32x4  __attribute__((ext_vector_type(4)));

static __device__ inline f32x16 fzero16() {
    f32x16 v;
    #pragma unroll
    for (int i = 0; i < 16; ++i) v[i] = 0.f;
    return v;
}

static __device__ inline uint cvtpk_bf16(float lo, float hi) {
    uint r;
    asm("v_cvt_pk_bf16_f32 %0, %1, %2" : "=v"(r) : "v"(lo), "v"(hi));
    return r;
}

static __device__ inline ushort f2bf(float f) {
    uint u = __builtin_bit_cast(uint, f);
    u = (u + 0x7FFFu + ((u >> 16) & 1u)) >> 16;
    return (ushort)u;
}

// ---------------------------------------------------------------------------
// Kernel 1: projection + chessboard gather + ReLU, 2-way OUTPUT split.
// 128 threads = 2 waves per (cg, j): wave 0 computes outputs 0-9, wave 1
// outputs 10-19 — DISJOINT outputs (unlike r7's failed c-split: no LDS
// combine, no sync, both waves store). Per-wave FMA halves, wave count
// doubles to 2304 (2.25/SIMD) -> latency exposure halves. Wave 1's x loads
// are L1 hits (same block). Weights direct via wave-uniform s_load path.
// ---------------------------------------------------------------------------
__global__ __launch_bounds__(128) void proj_kernel(
    const float* __restrict__ x,
    const float* __restrict__ Wq, const float* __restrict__ bq,
    const float* __restrict__ Wk, const float* __restrict__ bk,
    const float* __restrict__ Wv, const float* __restrict__ bv,
    _Float16* __restrict__ qh, _Float16* __restrict__ kh,
    ushort* __restrict__ vws)
{
    const int bid0 = blockIdx.x;
    const int bid = (bid0 & 7) * (PBLK / 8) + (bid0 >> 3);  // 144 consecutive per XCD
    const int cg = bid >> 2;
    const int j  = bid & 3;
    const int tid = threadIdx.x;
    const int wv = tid >> 6;                  // output-half: 0 -> o 0-9, 1 -> o 10-19
    const int lane = tid & 63;
    const int C = cg * 64 + lane;             // 0..18431
    const int b = C / 9216;
    const int cp = C - b * 9216;              // h*48 + wq
    const int h = cp / 48;
    const int wq = cp - h * 48;
    const int n = (h & 3) * 4 + j;
    const int l = (h >> 2) * 48 + wq;
    const int bn = b * 16 + n;

    const float* xp = x + (size_t)b * 64 * 36864 + cp * 4 + j;

    float acc[10] = {};
    if (j < 3) {
        const float* wbase = Wv + (j * 20 + wv * 10) * 64;
        #pragma unroll 4
        for (int c = 0; c < 64; ++c) {
            const float xv = xp[(size_t)c * 36864];
            #pragma unroll
            for (int o = 0; o < 10; ++o)
                acc[o] += wbase[o * 64 + c] * xv;
        }
    } else if (wv == 0) {
        // global o 0-9: V rows 60-63, then q rows 0-5
        #pragma unroll 4
        for (int c = 0; c < 64; ++c) {
            const float xv = xp[(size_t)c * 36864];
            #pragma unroll
            for (int o = 0; o < 4; ++o) acc[o] += Wv[(60 + o) * 64 + c] * xv;
            #pragma unroll
            for (int o = 0; o < 6; ++o) acc[4 + o] += Wq[o * 64 + c] * xv;
        }
    } else {
        // global o 10-19: q rows 6-7, then k rows 0-7
        #pragma unroll 4
        for (int c = 0; c < 64; ++c) {
            const float xv = xp[(size_t)c * 36864];
            acc[0] += Wq[6 * 64 + c] * xv;
            acc[1] += Wq[7 * 64 + c] * xv;
            #pragma unroll
            for (int o = 0; o < 8; ++o) acc[2 + o] += Wk[o * 64 + c] * xv;
        }
    }

    const int mt = l >> 6;
    const int ks4 = (l >> 4) & 3;
    const int m16 = l & 15;
    ushort* vd = vws + (((size_t)bn * NMT + mt) * 4 + ks4) * 1024 + m16;
    _Float16* qd = qh + ((size_t)bn * L_ + l) * 8;

    if (j < 3) {
        const int ob = 20 * j + wv * 10;
        #pragma unroll
        for (int o = 0; o < 10; ++o)
            vd[(ob + o) * 16] = f2bf(fmaxf(acc[o] + bv[ob + o], 0.f));
    } else if (wv == 0) {
        #pragma unroll
        for (int o = 0; o < 4; ++o)
            vd[(60 + o) * 16] = f2bf(fmaxf(acc[o] + bv[60 + o], 0.f));
        #pragma unroll
        for (int o = 0; o < 6; ++o)
            qd[o] = (_Float16)fmaxf((acc[4 + o] + bq[o]) * LOG2E, 0.f);
    } else {
        qd[6] = (_Float16)fmaxf((acc[0] + bq[6]) * LOG2E, 0.f);
        qd[7] = (_Float16)fmaxf((acc[1] + bq[7]) * LOG2E, 0.f);
        half8 kv;
        #pragma unroll
        for (int o = 0; o < 8; ++o)
            kv[o] = (_Float16)fmaxf(acc[2 + o] + bk[o], 0.f);
        *(half8*)(kh + ((size_t)bn * L_ + l) * 8) = kv;
    }
}

// ---------------------------------------------------------------------------
// Kernel 2 (r12, UNCHANGED — proven best): 4 waves per (bn, 32 q-rows).
// Partner-concurrent XCD mapping: XCD x = bid0&7 owns group G = (b, h&3);
// the 4 chessboard j-partners are consecutive same-XCD slots -> partial-line
// writes merge in L2 -> full-line HBM writes. Cross-tile score pipeline;
// V ring-4 prefetched 3 stages ahead; in-LDS transpose epilogue.
// ---------------------------------------------------------------------------
__global__ __launch_bounds__(256) void attn_kernel(
    const _Float16* __restrict__ qh, const _Float16* __restrict__ kh,
    const ushort* __restrict__ vws, const float* __restrict__ x,
    const float* __restrict__ gamma_p, float* __restrict__ out)
{
    __shared__ float red[4][64][17];              // 17408 B; reused as lds_o[64][33]
    float* lds_o = &red[0][0][0];

    const int tid = threadIdx.x;
    const int wid = tid >> 6;
    const int lane = tid & 63;
    const int r32 = lane & 31;
    const int hi = lane >> 5;

    // partner-concurrent XCD mapping (see header comment)
    const int bid0 = blockIdx.x;
    const int xg = bid0 & 7;            // XCD / group G = b*4 + (h&3)
    const int s  = bid0 >> 3;           // 0..287
    const int j4 = s & 3;               // chessboard j = n&3
    const int lt = s >> 2;              // 0..71
    const int b  = xg >> 2;
    const int n  = (xg & 3) * 4 + j4;
    const int bn = b * 16 + n;
    const int qrow0 = lt * QROWS;

    const _Float16* qb = qh + (size_t)bn * L_ * 8;
    const _Float16* kb = kh + (size_t)bn * L_ * 8;
    const ushort* vaddr = vws + (size_t)bn * NMT * 4096 + r32 * 16 + hi * 8;

    half8 qfrag;
    #pragma unroll
    for (int i = 0; i < 8; ++i) qfrag[i] = (_Float16)0.f;
    if (hi == 0) qfrag = *(const half8*)(qb + (qrow0 + r32) * 8);

    f32x16 acc0 = fzero16(), acc1 = fzero16();
    float psum = 0.f;

    half8 kf0n, kf1n;
    #pragma unroll
    for (int i = 0; i < 8; ++i) { kf0n[i] = (_Float16)0.f; kf1n[i] = (_Float16)0.f; }

    // prologue: K(tile wid) -> scores for tile 0; V stages 0,1,2 preloaded
    if (hi == 0) {
        kf0n = *(const half8*)(kb + (wid * 64 + r32) * 8);
        kf1n = *(const half8*)(kb + (wid * 64 + 32 + r32) * 8);
    }
    f32x16 s0 = __builtin_amdgcn_mfma_f32_32x32x16_f16(kf0n, qfrag, fzero16(), 0, 0, 0);
    f32x16 s1 = __builtin_amdgcn_mfma_f32_32x32x16_f16(kf1n, qfrag, fzero16(), 0, 0, 0);

    bf16x8 vb0[4], vb1[4];
    vb0[0] = *(const bf16x8*)(vaddr + wid * 4096);
    vb1[0] = *(const bf16x8*)(vaddr + wid * 4096 + 512);
    vb0[1] = *(const bf16x8*)(vaddr + wid * 4096 + 1024);
    vb1[1] = *(const bf16x8*)(vaddr + wid * 4096 + 1024 + 512);
    vb0[2] = *(const bf16x8*)(vaddr + wid * 4096 + 2048);
    vb1[2] = *(const bf16x8*)(vaddr + wid * 4096 + 2048 + 512);

    #pragma unroll 1
    for (int t = 0; t < NMT / 4; ++t) {
        const int mt  = 4 * t + wid;
        const int mtn = (t < NMT / 4 - 1) ? mt + 4 : mt;   // clamped next tile

        if (hi == 0) {   // masked K prefetch for t+1 (hi lanes stay zero)
            kf0n = *(const half8*)(kb + (mtn * 64 + r32) * 8);
            kf1n = *(const half8*)(kb + (mtn * 64 + 32 + r32) * 8);
        }

        // stage: consume score half SV[HALF] + V slot KS; load the V fragment
        // for global stage g+3 into slot (KS+3)&3 (freed at stage g-1).
        #define STAGE(KS, SV, HALF, LS, LOFF)                                  \
        {                                                                      \
            const bf16x8 nv0 = *(const bf16x8*)(vaddr + (LOFF));               \
            const bf16x8 nv1 = *(const bf16x8*)(vaddr + (LOFF) + 512);         \
            float e[8];                                                        \
            _Pragma("unroll")                                                  \
            for (int i = 0; i < 8; ++i)                                        \
                e[i] = __builtin_amdgcn_exp2f(SV[(HALF) * 8 + i]);             \
            psum += ((e[0] + e[1]) + (e[2] + e[3]))                            \
                  + ((e[4] + e[5]) + (e[6] + e[7]));                           \
            const uint pb0 = cvtpk_bf16(e[0], e[1]);                           \
            const uint pb1 = cvtpk_bf16(e[2], e[3]);                           \
            const uint pa0 = cvtpk_bf16(e[4], e[5]);                           \
            const uint pa1 = cvtpk_bf16(e[6], e[7]);                           \
            const u32x2 q0 = __builtin_amdgcn_permlane32_swap(pa0, pb0, false, false); \
            const u32x2 q1 = __builtin_amdgcn_permlane32_swap(pa1, pb1, false, false); \
            u32x4 tt;                                                          \
            tt[0] = q0.y; tt[1] = q1.y; tt[2] = q0.x; tt[3] = q1.x;            \
            const bf16x8 pa = __builtin_bit_cast(bf16x8, tt);                  \
            __builtin_amdgcn_s_setprio(1);                                     \
            acc0 = __builtin_amdgcn_mfma_f32_32x32x16_bf16(pa, vb0[KS], acc0, 0, 0, 0); \
            acc1 = __builtin_amdgcn_mfma_f32_32x32x16_bf16(pa, vb1[KS], acc1, 0, 0, 0); \
            __builtin_amdgcn_s_setprio(0);                                     \
            vb0[LS] = nv0; vb1[LS] = nv1;                                      \
        }

        STAGE(0, s0, 0, 3, mt * 4096 + 3072)
        STAGE(1, s0, 1, 0, mtn * 4096)
        // s0 consumed -> compute tile t+1 scores (keys 0..31) on MFMA pipe
        s0 = __builtin_amdgcn_mfma_f32_32x32x16_f16(kf0n, qfrag, fzero16(), 0, 0, 0);
        STAGE(2, s1, 0, 1, mtn * 4096 + 1024)
        STAGE(3, s1, 1, 2, mtn * 4096 + 2048)
        s1 = __builtin_amdgcn_mfma_f32_32x32x16_f16(kf1n, qfrag, fzero16(), 0, 0, 0);
        #undef STAGE
    }

    // per-wave full row sum (lanes r and r+32 hold the two key halves)
    const uint pu = __builtin_bit_cast(uint, psum);
    const u32x2 pc = __builtin_amdgcn_permlane32_swap(pu, pu, false, false);
    const float other = __builtin_bit_cast(float, (hi == 0) ? pc.x : pc.y);
    const float wsum = psum + other;

    // ---- 4-way cross-wave combine through LDS (two rounds) ----
    {
        float* dst = &red[wid][lane][0];
        #pragma unroll
        for (int r = 0; r < 16; ++r) dst[r] = acc0[r];
        dst[16] = wsum;
    }
    __syncthreads();

    float rtot = 0.f;
    #pragma unroll
    for (int w4 = 0; w4 < 4; ++w4) rtot += red[w4][lane][16];
    const float rinv = 1.0f / rtot;

    const int sw = wid & 1;           // sub-row half: r in [8*sw, 8*sw+8)
    float fin[8];
    if (wid < 2) {
        #pragma unroll
        for (int i = 0; i < 8; ++i)
            fin[i] = red[0][lane][8 * sw + i] + red[1][lane][8 * sw + i]
                   + red[2][lane][8 * sw + i] + red[3][lane][8 * sw + i];
    }
    __syncthreads();

    {
        float* dst = &red[wid][lane][0];
        #pragma unroll
        for (int r = 0; r < 16; ++r) dst[r] = acc1[r];
    }
    __syncthreads();

    if (wid >= 2) {
        #pragma unroll
        for (int i = 0; i < 8; ++i)
            fin[i] = red[0][lane][8 * sw + i] + red[1][lane][8 * sw + i]
                   + red[2][lane][8 * sw + i] + red[3][lane][8 * sw + i];
    }
    __syncthreads();

    // ---- in-LDS transpose: lds_o[ch][Rg] = normalized value ----
    {
        const int chw = r32 + ((wid >= 2) ? 32 : 0);
        #pragma unroll
        for (int i = 0; i < 8; ++i) {
            const int r = 8 * sw + i;
            const int Rg = (r & 3) + 8 * (r >> 2) + 4 * hi;
            const float ri = __shfl(rinv, Rg, 64);
            lds_o[chw * 33 + Rg] = fin[i] * ri;
        }
    }
    __syncthreads();

    // ---- minimal-line epilogue: lanes gl-major, 2 ch per instr ----
    const int gl = lane & 31;
    const int ch2 = lane >> 5;
    const int glf = qrow0 + gl;
    const int hh = (glf / WQ_) * 4 + (n >> 2);
    const int ww = (glf % WQ_) * 4 + (n & 3);
    const float g = gamma_p[0];
    const size_t base = ((size_t)b * C_ * H_ + hh) * W_ + ww;
    #pragma unroll
    for (int io = 0; io < 8; ++io) {
        const int ch = io * 8 + wid * 2 + ch2;
        const size_t o = base + (size_t)ch * (H_ * W_);
        out[o] = g * lds_o[ch * 33 + gl] + x[o];
    }
}

extern "C" void kernel_launch(void* const* d_in, const int* in_sizes, int n_in,
                              void* d_out, int out_size, void* d_ws, size_t ws_size,
                              hipStream_t stream) {
    const float* x  = (const float*)d_in[0];
    const float* Wq = (const float*)d_in[1];
    const float* bq = (const float*)d_in[2];
    const float* Wk = (const float*)d_in[3];
    const float* bk = (const float*)d_in[4];
    const float* Wv = (const float*)d_in[5];
    const float* bv = (const float*)d_in[6];
    const float* gamma = (const float*)d_in[7];
    float* out = (float*)d_out;

    // ws: qh | kh | v frag-tiled
    _Float16* qh = (_Float16*)d_ws;
    _Float16* kh = qh + (size_t)32 * L_ * 8;
    ushort*   vb = (ushort*)(kh + (size_t)32 * L_ * 8);

    proj_kernel<<<dim3(PBLK), dim3(128), 0, stream>>>(
        x, Wq, bq, Wk, bk, Wv, bv, qh, kh, vb);
    attn_kernel<<<dim3(NBLK), dim3(256), 0, stream>>>(qh, kh, vb, x, gamma, out);
}

// Round 18
// 63.543 us; speedup vs baseline: 1.1689x; 1.1689x over previous
//
#include <hip/hip_runtime.h>

#define LOG2E 1.44269504088896340736f

constexpr int C_ = 64, H_ = 192, W_ = 192;
constexpr int WQ_ = 48, L_ = 2304;          // 48*48 tokens per offset
constexpr int KVB = 64;                      // key tile
constexpr int NMT = L_ / KVB;                // 36 key tiles
constexpr int QROWS = 32;                    // q-rows per block
constexpr int NQT = L_ / QROWS;              // 72
constexpr int NBLK = 32 * NQT;               // 2304 attn blocks
constexpr int NCOL = 18432;                  // x float4-columns: 2*192*48
constexpr int PBLK = (NCOL / 64) * 4;        // proj blocks: 288 col-groups x 4 j

typedef _Float16 half8  __attribute__((ext_vector_type(8)));
typedef short    bf16x8 __attribute__((ext_vector_type(8)));
typedef float    f32x16 __attribute__((ext_vector_type(16)));
typedef uint     u32x2  __attribute__((ext_vector_type(2)));
typedef uint     u32x4  __attribute__((ext_vector_type(4)));

static __device__ inline f32x16 fzero16() {
    f32x16 v;
    #pragma unroll
    for (int i = 0; i < 16; ++i) v[i] = 0.f;
    return v;
}

static __device__ inline uint cvtpk_bf16(float lo, float hi) {
    uint r;
    asm("v_cvt_pk_bf16_f32 %0, %1, %2" : "=v"(r) : "v"(lo), "v"(hi));
    return r;
}

static __device__ inline ushort f2bf(float f) {
    uint u = __builtin_bit_cast(uint, f);
    u = (u + 0x7FFFu + ((u >> 16) & 1u)) >> 16;
    return (ushort)u;
}

// ---------------------------------------------------------------------------
// Kernel 1 (r16 proven, ~10.5 us): projection + chessboard gather + ReLU.
// Weights read DIRECTLY from original Wq/Wk/Wv layouts via wave-uniform
// scalar loads (s_load path; 16 KB, scalar-cache-hot). LOG2E q-prescale
// folded into the epilogue. One 64-lane block per (column-group cg, j);
// x reads L2-shared across the 4 j-blocks (co-XCD via swizzle).
// NOTE: proj parallelization attempts all failed — r7 c-split (LDS combine
// cost), r13 full hoist (VGPR lifetime), r15 unroll16 (neutral), r17 o-split
// (duplicated gather latency). 1 wave/block is this kernel's optimum.
// ---------------------------------------------------------------------------
__global__ __launch_bounds__(64) void proj_kernel(
    const float* __restrict__ x,
    const float* __restrict__ Wq, const float* __restrict__ bq,
    const float* __restrict__ Wk, const float* __restrict__ bk,
    const float* __restrict__ Wv, const float* __restrict__ bv,
    _Float16* __restrict__ qh, _Float16* __restrict__ kh,
    ushort* __restrict__ vws)
{
    const int bid0 = blockIdx.x;
    const int bid = (bid0 & 7) * (PBLK / 8) + (bid0 >> 3);  // 144 consecutive per XCD
    const int cg = bid >> 2;
    const int j  = bid & 3;
    const int lane = threadIdx.x;
    const int C = cg * 64 + lane;             // 0..18431
    const int b = C / 9216;
    const int cp = C - b * 9216;              // h*48 + wq
    const int h = cp / 48;
    const int wq = cp - h * 48;
    const int n = (h & 3) * 4 + j;
    const int l = (h >> 2) * 48 + wq;
    const int bn = b * 16 + n;

    const float* xp = x + (size_t)b * 64 * 36864 + cp * 4 + j;

    float acc[20] = {};
    if (j < 3) {
        const float* wbase = Wv + j * 20 * 64;     // rows j*20 .. j*20+19
        #pragma unroll 4
        for (int c = 0; c < 64; ++c) {
            const float xv = xp[(size_t)c * 36864];
            #pragma unroll
            for (int o = 0; o < 20; ++o)
                acc[o] += wbase[o * 64 + c] * xv;
        }
    } else {
        #pragma unroll 4
        for (int c = 0; c < 64; ++c) {
            const float xv = xp[(size_t)c * 36864];
            #pragma unroll
            for (int o = 0; o < 4; ++o)
                acc[o] += Wv[(60 + o) * 64 + c] * xv;
            #pragma unroll
            for (int o = 0; o < 8; ++o)
                acc[4 + o] += Wq[o * 64 + c] * xv;
            #pragma unroll
            for (int o = 0; o < 8; ++o)
                acc[12 + o] += Wk[o * 64 + c] * xv;
        }
    }

    const int mt = l >> 6;
    const int ks4 = (l >> 4) & 3;
    const int m16 = l & 15;
    ushort* vd = vws + (((size_t)bn * NMT + mt) * 4 + ks4) * 1024 + m16;

    if (j < 3) {
        #pragma unroll
        for (int o = 0; o < 20; ++o)
            vd[(20 * j + o) * 16] = f2bf(fmaxf(acc[o] + bv[20 * j + o], 0.f));
    } else {
        #pragma unroll
        for (int o = 0; o < 4; ++o)
            vd[(60 + o) * 16] = f2bf(fmaxf(acc[o] + bv[60 + o], 0.f));
        half8 qv, kv;
        #pragma unroll
        for (int o = 0; o < 8; ++o) {
            qv[o] = (_Float16)(fmaxf((acc[4 + o] + bq[o]) * LOG2E, 0.f));
            kv[o] = (_Float16)fmaxf(acc[12 + o] + bk[o], 0.f);
        }
        *(half8*)(qh + ((size_t)bn * L_ + l) * 8) = qv;
        *(half8*)(kh + ((size_t)bn * L_ + l) * 8) = kv;
    }
}

// ---------------------------------------------------------------------------
// Kernel 2 (r12, UNCHANGED — proven best): 4 waves per (bn, 32 q-rows).
// Partner-concurrent XCD mapping: XCD x = bid0&7 owns group G = (b, h&3);
// the 4 chessboard j-partners are consecutive same-XCD slots -> partial-line
// writes merge in L2 -> full-line HBM writes. Cross-tile score pipeline;
// V ring-4 prefetched 3 stages ahead; in-LDS transpose epilogue.
// ---------------------------------------------------------------------------
__global__ __launch_bounds__(256) void attn_kernel(
    const _Float16* __restrict__ qh, const _Float16* __restrict__ kh,
    const ushort* __restrict__ vws, const float* __restrict__ x,
    const float* __restrict__ gamma_p, float* __restrict__ out)
{
    __shared__ float red[4][64][17];              // 17408 B; reused as lds_o[64][33]
    float* lds_o = &red[0][0][0];

    const int tid = threadIdx.x;
    const int wid = tid >> 6;
    const int lane = tid & 63;
    const int r32 = lane & 31;
    const int hi = lane >> 5;

    // partner-concurrent XCD mapping (see header comment)
    const int bid0 = blockIdx.x;
    const int xg = bid0 & 7;            // XCD / group G = b*4 + (h&3)
    const int s  = bid0 >> 3;           // 0..287
    const int j4 = s & 3;               // chessboard j = n&3
    const int lt = s >> 2;              // 0..71
    const int b  = xg >> 2;
    const int n  = (xg & 3) * 4 + j4;
    const int bn = b * 16 + n;
    const int qrow0 = lt * QROWS;

    const _Float16* qb = qh + (size_t)bn * L_ * 8;
    const _Float16* kb = kh + (size_t)bn * L_ * 8;
    const ushort* vaddr = vws + (size_t)bn * NMT * 4096 + r32 * 16 + hi * 8;

    half8 qfrag;
    #pragma unroll
    for (int i = 0; i < 8; ++i) qfrag[i] = (_Float16)0.f;
    if (hi == 0) qfrag = *(const half8*)(qb + (qrow0 + r32) * 8);

    f32x16 acc0 = fzero16(), acc1 = fzero16();
    float psum = 0.f;

    half8 kf0n, kf1n;
    #pragma unroll
    for (int i = 0; i < 8; ++i) { kf0n[i] = (_Float16)0.f; kf1n[i] = (_Float16)0.f; }

    // prologue: K(tile wid) -> scores for tile 0; V stages 0,1,2 preloaded
    if (hi == 0) {
        kf0n = *(const half8*)(kb + (wid * 64 + r32) * 8);
        kf1n = *(const half8*)(kb + (wid * 64 + 32 + r32) * 8);
    }
    f32x16 s0 = __builtin_amdgcn_mfma_f32_32x32x16_f16(kf0n, qfrag, fzero16(), 0, 0, 0);
    f32x16 s1 = __builtin_amdgcn_mfma_f32_32x32x16_f16(kf1n, qfrag, fzero16(), 0, 0, 0);

    bf16x8 vb0[4], vb1[4];
    vb0[0] = *(const bf16x8*)(vaddr + wid * 4096);
    vb1[0] = *(const bf16x8*)(vaddr + wid * 4096 + 512);
    vb0[1] = *(const bf16x8*)(vaddr + wid * 4096 + 1024);
    vb1[1] = *(const bf16x8*)(vaddr + wid * 4096 + 1024 + 512);
    vb0[2] = *(const bf16x8*)(vaddr + wid * 4096 + 2048);
    vb1[2] = *(const bf16x8*)(vaddr + wid * 4096 + 2048 + 512);

    #pragma unroll 1
    for (int t = 0; t < NMT / 4; ++t) {
        const int mt  = 4 * t + wid;
        const int mtn = (t < NMT / 4 - 1) ? mt + 4 : mt;   // clamped next tile

        if (hi == 0) {   // masked K prefetch for t+1 (hi lanes stay zero)
            kf0n = *(const half8*)(kb + (mtn * 64 + r32) * 8);
            kf1n = *(const half8*)(kb + (mtn * 64 + 32 + r32) * 8);
        }

        // stage: consume score half SV[HALF] + V slot KS; load the V fragment
        // for global stage g+3 into slot (KS+3)&3 (freed at stage g-1).
        #define STAGE(KS, SV, HALF, LS, LOFF)                                  \
        {                                                                      \
            const bf16x8 nv0 = *(const bf16x8*)(vaddr + (LOFF));               \
            const bf16x8 nv1 = *(const bf16x8*)(vaddr + (LOFF) + 512);         \
            float e[8];                                                        \
            _Pragma("unroll")                                                  \
            for (int i = 0; i < 8; ++i)                                        \
                e[i] = __builtin_amdgcn_exp2f(SV[(HALF) * 8 + i]);             \
            psum += ((e[0] + e[1]) + (e[2] + e[3]))                            \
                  + ((e[4] + e[5]) + (e[6] + e[7]));                           \
            const uint pb0 = cvtpk_bf16(e[0], e[1]);                           \
            const uint pb1 = cvtpk_bf16(e[2], e[3]);                           \
            const uint pa0 = cvtpk_bf16(e[4], e[5]);                           \
            const uint pa1 = cvtpk_bf16(e[6], e[7]);                           \
            const u32x2 q0 = __builtin_amdgcn_permlane32_swap(pa0, pb0, false, false); \
            const u32x2 q1 = __builtin_amdgcn_permlane32_swap(pa1, pb1, false, false); \
            u32x4 tt;                                                          \
            tt[0] = q0.y; tt[1] = q1.y; tt[2] = q0.x; tt[3] = q1.x;            \
            const bf16x8 pa = __builtin_bit_cast(bf16x8, tt);                  \
            __builtin_amdgcn_s_setprio(1);                                     \
            acc0 = __builtin_amdgcn_mfma_f32_32x32x16_bf16(pa, vb0[KS], acc0, 0, 0, 0); \
            acc1 = __builtin_amdgcn_mfma_f32_32x32x16_bf16(pa, vb1[KS], acc1, 0, 0, 0); \
            __builtin_amdgcn_s_setprio(0);                                     \
            vb0[LS] = nv0; vb1[LS] = nv1;                                      \
        }

        STAGE(0, s0, 0, 3, mt * 4096 + 3072)
        STAGE(1, s0, 1, 0, mtn * 4096)
        // s0 consumed -> compute tile t+1 scores (keys 0..31) on MFMA pipe
        s0 = __builtin_amdgcn_mfma_f32_32x32x16_f16(kf0n, qfrag, fzero16(), 0, 0, 0);
        STAGE(2, s1, 0, 1, mtn * 4096 + 1024)
        STAGE(3, s1, 1, 2, mtn * 4096 + 2048)
        s1 = __builtin_amdgcn_mfma_f32_32x32x16_f16(kf1n, qfrag, fzero16(), 0, 0, 0);
        #undef STAGE
    }

    // per-wave full row sum (lanes r and r+32 hold the two key halves)
    const uint pu = __builtin_bit_cast(uint, psum);
    const u32x2 pc = __builtin_amdgcn_permlane32_swap(pu, pu, false, false);
    const float other = __builtin_bit_cast(float, (hi == 0) ? pc.x : pc.y);
    const float wsum = psum + other;

    // ---- 4-way cross-wave combine through LDS (two rounds) ----
    {
        float* dst = &red[wid][lane][0];
        #pragma unroll
        for (int r = 0; r < 16; ++r) dst[r] = acc0[r];
        dst[16] = wsum;
    }
    __syncthreads();

    float rtot = 0.f;
    #pragma unroll
    for (int w4 = 0; w4 < 4; ++w4) rtot += red[w4][lane][16];
    const float rinv = 1.0f / rtot;

    const int sw = wid & 1;           // sub-row half: r in [8*sw, 8*sw+8)
    float fin[8];
    if (wid < 2) {
        #pragma unroll
        for (int i = 0; i < 8; ++i)
            fin[i] = red[0][lane][8 * sw + i] + red[1][lane][8 * sw + i]
                   + red[2][lane][8 * sw + i] + red[3][lane][8 * sw + i];
    }
    __syncthreads();

    {
        float* dst = &red[wid][lane][0];
        #pragma unroll
        for (int r = 0; r < 16; ++r) dst[r] = acc1[r];
    }
    __syncthreads();

    if (wid >= 2) {
        #pragma unroll
        for (int i = 0; i < 8; ++i)
            fin[i] = red[0][lane][8 * sw + i] + red[1][lane][8 * sw + i]
                   + red[2][lane][8 * sw + i] + red[3][lane][8 * sw + i];
    }
    __syncthreads();

    // ---- in-LDS transpose: lds_o[ch][Rg] = normalized value ----
    {
        const int chw = r32 + ((wid >= 2) ? 32 : 0);
        #pragma unroll
        for (int i = 0; i < 8; ++i) {
            const int r = 8 * sw + i;
            const int Rg = (r & 3) + 8 * (r >> 2) + 4 * hi;
            const float ri = __shfl(rinv, Rg, 64);
            lds_o[chw * 33 + Rg] = fin[i] * ri;
        }
    }
    __syncthreads();

    // ---- minimal-line epilogue: lanes gl-major, 2 ch per instr ----
    const int gl = lane & 31;
    const int ch2 = lane >> 5;
    const int glf = qrow0 + gl;
    const int hh = (glf / WQ_) * 4 + (n >> 2);
    const int ww = (glf % WQ_) * 4 + (n & 3);
    const float g = gamma_p[0];
    const size_t base = ((size_t)b * C_ * H_ + hh) * W_ + ww;
    #pragma unroll
    for (int io = 0; io < 8; ++io) {
        const int ch = io * 8 + wid * 2 + ch2;
        const size_t o = base + (size_t)ch * (H_ * W_);
        out[o] = g * lds_o[ch * 33 + gl] + x[o];
    }
}

extern "C" void kernel_launch(void* const* d_in, const int* in_sizes, int n_in,
                              void* d_out, int out_size, void* d_ws, size_t ws_size,
                              hipStream_t stream) {
    const float* x  = (const float*)d_in[0];
    const float* Wq = (const float*)d_in[1];
    const float* bq = (const float*)d_in[2];
    const float* Wk = (const float*)d_in[3];
    const float* bk = (const float*)d_in[4];
    const float* Wv = (const float*)d_in[5];
    const float* bv = (const float*)d_in[6];
    const float* gamma = (const float*)d_in[7];
    float* out = (float*)d_out;

    // ws: qh | kh | v frag-tiled
    _Float16* qh = (_Float16*)d_ws;
    _Float16* kh = qh + (size_t)32 * L_ * 8;
    ushort*   vb = (ushort*)(kh + (size_t)32 * L_ * 8);

    proj_kernel<<<dim3(PBLK), dim3(64), 0, stream>>>(
        x, Wq, bq, Wk, bk, Wv, bv, qh, kh, vb);
    attn_kernel<<<dim3(NBLK), dim3(256), 0, stream>>>(qh, kh, vb, x, gamma, out);
}